// Round 3
// baseline (238.102 us; speedup 1.0000x reference)
//
#include <hip/hip_runtime.h>
#include <hip/hip_bf16.h>
#include <math.h>

// Problem constants
#define BQ 4
#define NQ 100
#define MQ 50
#define HWSZ 65536
#define NP 112   // padded N rows in partials (7 x 16)
#define MP 64    // padded M (4 x 16)
#define DCLAMP 13.8155106f   // logit(1-1e-6) = -logit(1e-6)

typedef __attribute__((ext_vector_type(8))) short short8;
typedef __attribute__((ext_vector_type(4))) float f32x4;

// d = log(pm)-log(1-pm) = clamp(x, +-13.8155) EXACTLY (logit o clip o sigmoid).
// pm = sigmoid(clamp(x)); l1m = log(1-pm) = -log(1+e^xc).
__device__ __forceinline__ void xform2(float x, float& d, float& pm, float& l1m) {
    float xc = fminf(fmaxf(x, -DCLAMP), DCLAMP);
    d = xc;
    float e = __expf(xc);                       // in [1e-6, 1e6], no overflow
    float r = __builtin_amdgcn_rcpf(1.0f + e);
    pm = e * r;
    l1m = -__logf(1.0f + e);
}

// pack two floats -> two bf16 (RTNE) in one u32
__device__ __forceinline__ unsigned pk2(float a, float b) {
    __hip_bfloat162 h = __float22bfloat162_rn(float2{a, b});
    unsigned u;
    __builtin_memcpy(&u, &h, 4);
    return u;
}

// build a bf16x8 MFMA fragment from two float4
__device__ __forceinline__ short8 mk8(float4 a, float4 b) {
    union { short8 s; unsigned u[4]; } r;
    r.u[0] = pk2(a.x, a.y); r.u[1] = pk2(a.z, a.w);
    r.u[2] = pk2(b.x, b.y); r.u[3] = pk2(b.z, b.w);
    return r.s;
}

// build a bf16x8 MFMA fragment from 8 scalars
__device__ __forceinline__ short8 mk8s(float a0, float a1, float a2, float a3,
                                       float a4, float a5, float a6, float a7) {
    union { short8 s; unsigned u[4]; } r;
    r.u[0] = pk2(a0, a1); r.u[1] = pk2(a2, a3);
    r.u[2] = pk2(a4, a5); r.u[3] = pk2(a6, a7);
    return r.s;
}

// Barrier-free, LDS-free main kernel. Each WAVE owns one n-tile (16 pred
// rows) and computes all 4 m-tiles itself; A is loaded directly from global
// in MFMA operand layout; sigmoid/log transform done once per element.
//
// Round-3 change: nch 128 -> 256 (workspace permitting). Round-2 showed the
// grid itself capped occupancy: 512 blocks x 7 waves = 14 waves/CU
// (2.65/SIMD), not enough TLP to hide the ~400-600 cy load latency behind
// ~250 cy of per-iter compute (all pipes <35% busy). 1024 blocks = 4
// blocks/CU = 28 waves/CU at VGPR<=64. Also: ts column sums distributed
// across waves 0..3 (one m-tile each) instead of all on wave 0.
__global__ __launch_bounds__(448)
void matcher_main(const float* __restrict__ pred_masks,  // [4][100][65536]
                  const float* __restrict__ tgt_masks,   // [4][50][65536]
                  float* __restrict__ part1,             // [4][nch][112][64]
                  float* __restrict__ part2,             // [4][nch][112][64]
                  float* __restrict__ rspart,            // [4][nch][112][2]
                  float* __restrict__ tspart,            // [4][nch][64]
                  int nch, int Kc)
{
    const int t     = threadIdx.x;
    const int lane  = t & 63;
    const int ntile = t >> 6;            // 0..6 : n-tile owned by this wave
    const int chunk = blockIdx.x;
    const int b     = blockIdx.y;
    const int r16   = lane & 15;         // row within tile (A) / col (B)
    const int kq8   = (lane >> 4) * 8;   // k offset of this lane's 8 elems
    const long kbase = (long)chunk * Kc;

    // A pointer: operand-layout direct load (row-clamped; clamped rows
    // produce garbage partials in rows 100..111 which are never read)
    const int arow = min(ntile * 16 + r16, NQ - 1);
    const float* ap = pred_masks + (((long)(b * NQ + arow)) << 16) + kbase + kq8;

    // B pointers, one per m-tile (mt=3 rows 50..63 clamp to 49; partial
    // cols 50..63 are never read)
    const float* bp[4];
    #pragma unroll
    for (int mt = 0; mt < 4; mt++) {
        const int brow = min(mt * 16 + r16, MQ - 1);
        bp[mt] = tgt_masks + (((long)(b * MQ + brow)) << 16) + kbase + kq8;
    }

    f32x4 acc1[4], acc2[4];   // indexed by m-tile; C = [16 n-rows x 64 m-cols]
    #pragma unroll
    for (int mt = 0; mt < 4; mt++) {
        acc1[mt] = (f32x4){0.f, 0.f, 0.f, 0.f};
        acc2[mt] = (f32x4){0.f, 0.f, 0.f, 0.f};
    }
    float rsl = 0.f, rsp = 0.f;
    float ts = 0.f;   // wave ntile<4 accumulates column sums for m-tile==ntile

    #pragma unroll 2
    for (int k = 0; k < Kc; k += 32) {
        // ---- issue all loads for this k-slab first ----
        const float4 a0 = *(const float4*)(ap + k);
        const float4 a1 = *(const float4*)(ap + k + 4);
        float4 bv[4][2];
        #pragma unroll
        for (int mt = 0; mt < 4; mt++) {
            bv[mt][0] = *(const float4*)(bp[mt] + k);
            bv[mt][1] = *(const float4*)(bp[mt] + k + 4);
        }

        // ---- transform A in-register (done once per element chip-wide) ----
        float d0,d1,d2,d3,d4,d5,d6,d7, p0,p1,p2,p3,p4,p5,p6,p7, l;
        xform2(a0.x, d0, p0, l); rsl += l; rsp += p0;
        xform2(a0.y, d1, p1, l); rsl += l; rsp += p1;
        xform2(a0.z, d2, p2, l); rsl += l; rsp += p2;
        xform2(a0.w, d3, p3, l); rsl += l; rsp += p3;
        xform2(a1.x, d4, p4, l); rsl += l; rsp += p4;
        xform2(a1.y, d5, p5, l); rsl += l; rsp += p5;
        xform2(a1.z, d6, p6, l); rsl += l; rsp += p6;
        xform2(a1.w, d7, p7, l); rsl += l; rsp += p7;
        const short8 fd = mk8s(d0,d1,d2,d3,d4,d5,d6,d7);
        const short8 fp = mk8s(p0,p1,p2,p3,p4,p5,p6,p7);

        // ---- 4 m-tiles x 2 matrices MFMA, all operands in registers ----
        #pragma unroll
        for (int mt = 0; mt < 4; mt++) {
            const short8 fb = mk8(bv[mt][0], bv[mt][1]);
            acc1[mt] = __builtin_amdgcn_mfma_f32_16x16x32_bf16(fd, fb, acc1[mt], 0, 0, 0);
            acc2[mt] = __builtin_amdgcn_mfma_f32_16x16x32_bf16(fp, fb, acc2[mt], 0, 0, 0);
        }

        // ---- ts column sums (exact: binary values). Wave-uniform branch,
        // compile-time register indices only (no scratch demotion). ----
        #pragma unroll
        for (int mt = 0; mt < 4; mt++) {
            if (ntile == mt) {
                ts += bv[mt][0].x + bv[mt][0].y + bv[mt][0].z + bv[mt][0].w
                    + bv[mt][1].x + bv[mt][1].y + bv[mt][1].z + bv[mt][1].w;
            }
        }
    }

    // ---- store C partials: C/D layout col=lane&15, row=(lane>>4)*4+reg ----
    const long pbase = ((long)(b * nch + chunk)) * NP * MP;
    const int nr0 = (lane >> 4) * 4;
    #pragma unroll
    for (int mt = 0; mt < 4; mt++) {
        const int mloc = mt * 16 + r16;
        #pragma unroll
        for (int r = 0; r < 4; r++) {
            const int ng = ntile * 16 + nr0 + r;
            part1[pbase + ng * MP + mloc] = acc1[mt][r];
            part2[pbase + ng * MP + mloc] = acc2[mt][r];
        }
    }

    // ---- row sums: lanes {r,r+16,r+32,r+48} hold row r's k-partials ----
    rsl += __shfl_xor(rsl, 16); rsl += __shfl_xor(rsl, 32);
    rsp += __shfl_xor(rsp, 16); rsp += __shfl_xor(rsp, 32);
    if (lane < 16) {
        const long rb = ((long)(b * nch + chunk) * NP + ntile * 16 + lane) * 2;
        rspart[rb + 0] = rsl;
        rspart[rb + 1] = rsp;
    }

    // ---- ts column-sum reduce: wave ntile handles m-tile ntile ----
    if (ntile < 4) {
        ts += __shfl_xor(ts, 16);
        ts += __shfl_xor(ts, 32);
        if (lane < 16)
            tspart[(long)(b * nch + chunk) * MP + ntile * 16 + lane] = ts;
    }
}

// Epilogue: one block per (b,n), 1024 threads; 16-way chunk-group reduction.
__global__ __launch_bounds__(1024)
void matcher_epilogue(const float* __restrict__ pred_logits, // [4][100][2]
                      const float* __restrict__ pred_style,  // [4][100][4]
                      const int*   __restrict__ styles,      // [4][50]
                      const float* __restrict__ part1,
                      const float* __restrict__ part2,
                      const float* __restrict__ rspart,
                      const float* __restrict__ tspart,
                      float* __restrict__ out, int nch)
{
    __shared__ float red1[16][64], red2[16][64], redt[16][64];
    __shared__ float slw[16], spw[16];

    const int blk = blockIdx.x;          // 0..399
    const int b = blk / NQ, n = blk % NQ;
    const int t = threadIdx.x;
    const int m = t & 63, cg = t >> 6;   // cg in 0..15

    float S1 = 0.f, S2 = 0.f, St = 0.f;
    for (int c = cg; c < nch; c += 16) {
        const long base = ((long)(b * nch + c) * NP + n) * MP + m;
        S1 += part1[base];
        S2 += part2[base];
        St += tspart[(long)(b * nch + c) * MP + m];
    }
    red1[cg][m] = S1; red2[cg][m] = S2; redt[cg][m] = St;

    // Sl/Sp across chunks: threads 0..nch-1 load, per-wave shuffle reduce
    float sl = 0.f, sp = 0.f;
    if (t < nch) {
        const float2 v = *(const float2*)&rspart[((long)(b * nch + t) * NP + n) * 2];
        sl = v.x; sp = v.y;
    }
    #pragma unroll
    for (int off = 32; off; off >>= 1) { sl += __shfl_down(sl, off); sp += __shfl_down(sp, off); }
    if ((t & 63) == 0) { slw[t >> 6] = sl; spw[t >> 6] = sp; }
    __syncthreads();

    if (t < MQ) {
        float Sl = 0.f, Sp = 0.f, s1 = 0.f, s2 = 0.f, st = 0.f;
        #pragma unroll
        for (int w = 0; w < 16; w++) {
            Sl += slw[w]; Sp += spw[w];
            s1 += red1[w][t]; s2 += red2[w][t]; st += redt[w][t];
        }

        // classification: -softmax(logits)[1]
        const float l0 = pred_logits[(b * NQ + n) * 2 + 0];
        const float l1 = pred_logits[(b * NQ + n) * 2 + 1];
        const float p1 = 1.0f / (1.0f + __expf(l0 - l1));

        // style: -softmax(style)[sid]
        const float* stp = &pred_style[(b * NQ + n) * 4];
        const float v0 = stp[0], v1 = stp[1], v2 = stp[2], v3 = stp[3];
        const float mx = fmaxf(fmaxf(v0, v1), fmaxf(v2, v3));
        const float e0 = __expf(v0 - mx), e1 = __expf(v1 - mx),
                    e2 = __expf(v2 - mx), e3 = __expf(v3 - mx);
        const float esum = e0 + e1 + e2 + e3;
        int sid = styles[b * MQ + t];
        sid = min(max(sid, 0), 3);
        const float ps = (sid == 0 ? e0 : sid == 1 ? e1 : sid == 2 ? e2 : e3) / esum;

        const float cost_mask = -(s1 + Sl) * (1.0f / (float)HWSZ);
        const float dice = 1.0f - (2.0f * s2 + 1.0f) / (Sp + st + 1.0f);

        float c = 2.0f * (-p1) + 5.0f * cost_mask + 5.0f * dice + 1.0f * (-ps);
        if (isnan(c)) c = 10000.0f;
        else if (isinf(c)) c = (c > 0.f) ? 10000.0f : -10000.0f;
        out[(b * NQ + n) * MQ + t] = c;
    }
}

extern "C" void kernel_launch(void* const* d_in, const int* in_sizes, int n_in,
                              void* d_out, int out_size, void* d_ws, size_t ws_size,
                              hipStream_t stream) {
    const float* pred_logits = (const float*)d_in[0];
    const float* pred_masks  = (const float*)d_in[1];
    const float* pred_style  = (const float*)d_in[2];
    const float* tgt_masks   = (const float*)d_in[3];
    const int*   styles      = (const int*)d_in[4];
    float* out = (float*)d_out;

    // ws layout: part1/part2 [4][nch][112][64], rspart [4][nch][112][2], tspart [4][nch][64]
    // nch=256 -> 1024 blocks = 4 blocks/CU = 28 waves/CU (occupancy was
    // grid-capped at 14 waves/CU with nch=128).
    int nch = 8;
    for (int cand = 256; cand >= 8; cand >>= 1) {
        size_t need = (size_t)cand * (2ull * BQ * NP * MP * 4ull
                                      + (size_t)BQ * NP * 2 * 4ull
                                      + (size_t)BQ * MP * 4ull);
        if (need <= ws_size) { nch = cand; break; }
    }
    const int Kc = HWSZ / nch;

    float* part1  = (float*)d_ws;
    float* part2  = part1 + (size_t)BQ * nch * NP * MP;
    float* rspart = part2 + (size_t)BQ * nch * NP * MP;
    float* tspart = rspart + (size_t)BQ * nch * NP * 2;

    dim3 grid(nch, BQ);
    matcher_main<<<grid, 448, 0, stream>>>(pred_masks, tgt_masks, part1, part2, rspart, tspart, nch, Kc);

    matcher_epilogue<<<BQ * NQ, 1024, 0, stream>>>(
        pred_logits, pred_style, styles, part1, part2, rspart, tspart, out, nch);
}